// Round 6
// baseline (336.585 us; speedup 1.0000x reference)
//
#include <hip/hip_runtime.h>

#define S_LEN 2048
#define NHEAD 16

typedef float f32x4 __attribute__((ext_vector_type(4)));
typedef __bf16 bf16x8 __attribute__((ext_vector_type(8)));
typedef __bf16 bf16x4 __attribute__((ext_vector_type(4)));

#define AS1 __attribute__((address_space(1)))
#define AS3 __attribute__((address_space(3)))

// async 16B/lane global->LDS; lds base wave-uniform (dest = base + lane*16)
__device__ __forceinline__ void gl2lds16(const void* g, void* l) {
    __builtin_amdgcn_global_load_lds((const AS1 unsigned int*)g,
                                     (AS3 unsigned int*)l, 16, 0, 0);
}
// barrier that leaves the newest N vmem loads in flight (AITER pattern).
// Loop bodies must contain NO other vmem ops or the static count breaks.
__device__ __forceinline__ void wb_leave4() {
    asm volatile("s_waitcnt vmcnt(4)\n\ts_barrier" ::: "memory");
}
__device__ __forceinline__ void wb_leave2() {
    asm volatile("s_waitcnt vmcnt(2)\n\ts_barrier" ::: "memory");
}
__device__ __forceinline__ void wb_drain() {
    asm volatile("s_waitcnt vmcnt(0)\n\ts_barrier" ::: "memory");
}

// ---------------- cast+swizzle A: q,k,v fp32[8192][1024] -> bf16, 16B chunks
// within each 64-elem k-segment permuted by (chunk ^ row&7) -------------------
__global__ __launch_bounds__(256) void cast_swizzle_kernel(
    const float* __restrict__ q, const float* __restrict__ k,
    const float* __restrict__ v, __bf16* __restrict__ out)
{
    int gid = blockIdx.x * 256 + threadIdx.x;
    int z   = gid >> 20;
    int rem = gid & 1048575;
    int r   = rem >> 7;
    int c   = rem & 127;
    const float* src = (z == 0 ? q : z == 1 ? k : v) + (size_t)r * 1024 + c * 8;
    float4 a = *(const float4*)src;
    float4 b = *(const float4*)(src + 4);
    bf16x8 t;
    t[0] = (__bf16)a.x; t[1] = (__bf16)a.y; t[2] = (__bf16)a.z; t[3] = (__bf16)a.w;
    t[4] = (__bf16)b.x; t[5] = (__bf16)b.y; t[6] = (__bf16)b.z; t[7] = (__bf16)b.w;
    int cp = (c & ~7) | ((c ^ r) & 7);
    *(bf16x8*)(out + (size_t)z * 8388608 + (size_t)r * 1024 + cp * 8) = t;
}

// ---------------- W transpose+cast+swizzle: W[k][n] f32 -> Wt[n][k] bf16 -----
__global__ __launch_bounds__(256) void transpose_cast_kernel(
    const float* __restrict__ W0, const float* __restrict__ W1,
    const float* __restrict__ W2, __bf16* __restrict__ Wt)
{
    int z = blockIdx.z;
    const float* W = (z == 0 ? W0 : z == 1 ? W1 : W2);
    __bf16* out = Wt + (size_t)z * 1048576;
    __shared__ float tile[32][33];
    int bx = blockIdx.x, by = blockIdx.y;
    int tid = threadIdx.x;
    int tx = tid & 31, ty = tid >> 5;
    for (int i = 0; i < 32; i += 8)
        tile[ty + i][tx] = W[(size_t)(by * 32 + ty + i) * 1024 + bx * 32 + tx];
    __syncthreads();
    if (tid < 128) {
        int nl = tid >> 2, kc = tid & 3;
        int n = bx * 32 + nl;
        int kbase = by * 32 + kc * 8;
        bf16x8 t;
        for (int j = 0; j < 8; j++) t[j] = (__bf16)tile[kc * 8 + j][nl];
        int cp = ((kbase >> 3) ^ n) & 7;
        *(bf16x8*)(out + (size_t)n * 1024 + (kbase & ~63) + cp * 8) = t;
    }
}

// ---------------- fused projection GEMM (z = 0:Q, 1:K, 2:V) ------------------
// BK=32, 3-slot LDS pipeline, 2-ahead prefetch, vmcnt-leave barriers.
// z==0 output pre-scaled by 0.125 (exact pow2; folds QK^T scale into Q).
__global__ __launch_bounds__(256, 3) void proj_gemm_kernel(
    const __bf16* __restrict__ Abf, const __bf16* __restrict__ Wt,
    __bf16* __restrict__ qw, __bf16* __restrict__ kw, __bf16* __restrict__ vt)
{
    int z = blockIdx.z;
    const __bf16* A = Abf + (size_t)z * 8388608;
    const __bf16* B = Wt + (size_t)z * 1048576;
    __shared__ __align__(16) char smem[49152];  // A slots 0..24575, B slots 24576.., T overlay

    int tid = threadIdx.x;
    int bm = blockIdx.x, bn = blockIdx.y;
    int wave = tid >> 6, lane = tid & 63;
    int wm = (wave >> 1) * 64, wn = (wave & 1) * 64;
    int lrow = lane & 15;
    int q4 = lane >> 4;
    int l4r = lane >> 2, j4 = lane & 3;

    // prefetch K-step kb (k0 = kb*32) into slot kb%3
    auto pf = [&](int kb) {
        int sl = kb % 3;
        int k0 = kb * 32;
        int segbyte = (k0 >> 6) * 128;
        int cbase = (k0 & 32) >> 3;             // 0 or 4
        for (int i = 0; i < 2; i++) {
            int r = wave * 32 + i * 16 + l4r;
            int cl = j4 ^ ((r >> 1) & 3);
            int phys = ((cbase + cl) ^ r) & 7;
            gl2lds16((const char*)A + (size_t)(bm * 128 + r) * 2048 + segbyte + phys * 16,
                     smem + sl * 8192 + wave * 2048 + i * 1024);
            gl2lds16((const char*)B + (size_t)(bn * 128 + r) * 2048 + segbyte + phys * 16,
                     smem + 24576 + sl * 8192 + wave * 2048 + i * 1024);
        }
    };

    f32x4 zero = {0.f, 0.f, 0.f, 0.f};
    f32x4 acc[4][4];
    for (int mt = 0; mt < 4; mt++)
        for (int nt = 0; nt < 4; nt++) acc[mt][nt] = zero;

    pf(0); pf(1);
    __syncthreads();
    for (int kb = 0; kb < 32; kb++) {
        if (kb == 31) wb_drain(); else wb_leave4();
        if (kb + 2 < 32) pf(kb + 2);
        int sA = (kb % 3) * 8192, sB = 24576 + (kb % 3) * 8192;
        bf16x8 af[4], bfv[4];
        for (int mt = 0; mt < 4; mt++) {
            int r = wm + mt * 16 + lrow;
            af[mt] = *(const bf16x8*)(smem + sA + r * 64 + (q4 ^ ((r >> 1) & 3)) * 16);
        }
        for (int nt = 0; nt < 4; nt++) {
            int r = wn + nt * 16 + lrow;
            bfv[nt] = *(const bf16x8*)(smem + sB + r * 64 + (q4 ^ ((r >> 1) & 3)) * 16);
        }
        for (int mt = 0; mt < 4; mt++)
            for (int nt = 0; nt < 4; nt++)
                acc[mt][nt] = __builtin_amdgcn_mfma_f32_16x16x32_bf16(
                    af[mt], bfv[nt], acc[mt][nt], 0, 0, 0);
    }
    __syncthreads();               // frag reads done before T overlay
    __bf16* T = (__bf16*)smem;     // row stride 136 elems (272 B)

    float oscale = (z == 0) ? 0.125f : 1.0f;
    int rowoff = q4 * 4;
    int b = bm >> 4;
    int s_base = (bm & 15) * 128;
    if (z < 2) {
        for (int mt = 0; mt < 4; mt++) {
            for (int nt = 0; nt < 4; nt++) {
                int n_local = wn + nt * 16 + lrow;
                int hl = n_local >> 6, d = n_local & 63;
                for (int reg = 0; reg < 4; reg++) {
                    int s_local = wm + mt * 16 + rowoff + reg;
                    int s = s_base + s_local;
                    int dp = (d & 7) | ((((d >> 3) ^ s) & 7) << 3);
                    T[s_local * 136 + hl * 64 + dp] = (__bf16)(acc[mt][nt][reg] * oscale);
                }
            }
        }
        __syncthreads();
        char* gq = (char*)(z == 0 ? qw : kw);
        for (int i = 0; i < 8; i++) {
            int id = tid + i * 256;
            int hl = id >> 10, r = (id >> 3) & 127, j = id & 7;
            float4 val = *(float4*)((char*)T + r * 272 + hl * 128 + j * 16);
            *(float4*)(gq + ((size_t)((b * 16 + bn * 2 + hl) * 2048) + s_base + r) * 128
                          + j * 16) = val;
        }
    } else {
        for (int mt = 0; mt < 4; mt++) {
            int s0 = wm + mt * 16 + rowoff;
            int seg = s0 >> 6, j0 = s0 & 63;
            for (int nt = 0; nt < 4; nt++) {
                int n_local = wn + nt * 16 + lrow;
                int d = n_local & 63;
                int hi = ((j0 >> 3) ^ d) & 7;
                bf16x4 pk;
                for (int reg = 0; reg < 4; reg++) pk[reg] = (__bf16)acc[mt][nt][reg];
                *(bf16x4*)&T[n_local * 136 + seg * 64 + hi * 8 + (j0 & 7)] = pk;
            }
        }
        __syncthreads();
        char* gv = (char*)vt;
        for (int i = 0; i < 8; i++) {
            int id = tid + i * 256;
            int nl = id >> 4, j = id & 15;
            int hl = nl >> 6, dv = nl & 63;
            float4 val = *(float4*)((char*)T + nl * 272 + j * 16);
            *(float4*)(gv + (((size_t)((b * 16 + bn * 2 + hl) * 64 + dv)) * 2048 + s_base) * 2
                          + j * 16) = val;
        }
    }
}

// ---------------- flash attention (constant-max softmax, S^T, 3-slot pipe) ---
// QW (pre-scaled 0.125), KW bf16 [B*H][S][64] swizzled; VT bf16 [B*H][64][S].
// p = exp(s - pen - 12): no per-step max/rescale (|logits| << 75).
// Degenerate rows (whole window masked -> l==0) fixed by indicator-P pass.
__global__ __launch_bounds__(256, 2) void attn_kernel(
    const __bf16* __restrict__ QW, const __bf16* __restrict__ KW,
    const __bf16* __restrict__ VT, const float* __restrict__ v_mask,
    const float* __restrict__ q_mask, float* __restrict__ out)
{
    int bx = blockIdx.x;
    int qb = (bx == 0) ? 0 : 32 - bx;   // deg-capable qb=0 first, then 31..1
    int bh = blockIdx.y;
    int b = bh >> 4, h = bh & 15;

    __shared__ __align__(16) __bf16 Ks[3][4096];
    __shared__ __align__(16) __bf16 Vs[3][4096];
    __shared__ __align__(16) __bf16 Ps[4096];   // Q staging, P tile, flag
    __shared__ __align__(16) float vms[2048];   // whole v_mask row for batch b

    int tid = threadIdx.x;
    int wave = tid >> 6, lane = tid & 63;
    int row0 = wave * 16;
    int mloc = lane & 15;            // this lane's query row (local)
    int q4 = lane >> 4;
    int rowoff = q4 * 4;
    int x7 = mloc & 7;
    int l8r = lane >> 3, l8c = lane & 7;

    const char* Qbase = (const char*)(QW + ((size_t)bh * S_LEN + qb * 64) * 64);
    const char* Kbase = (const char*)(KW + (size_t)bh * S_LEN * 64);
    const char* Vbase = (const char*)(VT + (size_t)bh * 64 * S_LEN);

    auto prefetchV = [&](int kb) {   // 2 vmem insts
        int sl = kb % 3;
        for (int i = 0; i < 2; i++) {
            int row = wave * 16 + i * 8 + l8r;
            gl2lds16(Vbase + (size_t)row * 4096 + kb * 128 + l8c * 16,
                     (char*)Vs[sl] + wave * 2048 + i * 1024);
        }
    };
    auto prefetch = [&](int kb) {    // 4 vmem insts
        int sl = kb % 3;
        for (int i = 0; i < 2; i++)
            gl2lds16(Kbase + kb * 8192 + wave * 2048 + i * 1024 + lane * 16,
                     (char*)Ks[sl] + wave * 2048 + i * 1024);
        prefetchV(kb);
    };

    // prologue staging: Q -> Ps region, v_mask row -> vms, tiles 0,1
    for (int i = 0; i < 2; i++)
        gl2lds16(Qbase + wave * 2048 + i * 1024 + lane * 16,
                 (char*)Ps + wave * 2048 + i * 1024);
    for (int i = 0; i < 2; i++)
        gl2lds16((const char*)v_mask + (size_t)b * 8192 + wave * 2048 + i * 1024 + lane * 16,
                 (char*)vms + wave * 2048 + i * 1024);
    prefetch(0);
    if (qb >= 1) prefetch(1);
    __syncthreads();

    bf16x8 qfr[2];
    for (int kc = 0; kc < 2; kc++)
        qfr[kc] = *(const bf16x8*)((const char*)Ps + (row0 + mloc) * 128 +
                                   (((kc * 4 + q4) ^ x7) << 4));

    float l_part = 0.f;
    f32x4 zero = {0.f, 0.f, 0.f, 0.f};
    f32x4 o_acc[4];
    for (int nt = 0; nt < 4; nt++) o_acc[nt] = zero;

    for (int kb = 0; kb <= qb; kb++) {
        if (kb == qb) wb_drain(); else wb_leave4();
        if (kb + 2 <= qb) prefetch(kb + 2);
        const char* Kb = (const char*)Ks[kb % 3];
        const char* Vb = (const char*)Vs[kb % 3];

        // penalties from LDS (key = kb*64 + nt*16 + q4*4 + reg)
        float pen[4][4];
        for (int nt = 0; nt < 4; nt++) {
            float4 vm4 = *(const float4*)&vms[kb * 64 + nt * 16 + q4 * 4];
            pen[nt][0] = fmaf(1.0f - vm4.x, 1.0e9f, 12.0f);
            pen[nt][1] = fmaf(1.0f - vm4.y, 1.0e9f, 12.0f);
            pen[nt][2] = fmaf(1.0f - vm4.z, 1.0e9f, 12.0f);
            pen[nt][3] = fmaf(1.0f - vm4.w, 1.0e9f, 12.0f);
        }

        f32x4 sacc[4];
        for (int nt = 0; nt < 4; nt++) sacc[nt] = zero;
        for (int kc = 0; kc < 2; kc++) {
            int sw = ((kc * 4 + q4) ^ x7) << 4;
            for (int nt = 0; nt < 4; nt++) {
                bf16x8 kfr = *(const bf16x8*)(Kb + (nt * 16 + mloc) * 128 + sw);
                sacc[nt] = __builtin_amdgcn_mfma_f32_16x16x32_bf16(kfr, qfr[kc], sacc[nt], 0, 0, 0);
            }
        }

        float p[4][4];
        for (int nt = 0; nt < 4; nt++)
            for (int reg = 0; reg < 4; reg++)
                p[nt][reg] = __expf(sacc[nt][reg] - pen[nt][reg]);
        if (kb == qb) {   // causal zeroing on the diagonal tile
            for (int nt = 0; nt < 4; nt++)
                for (int reg = 0; reg < 4; reg++)
                    if (nt * 16 + rowoff + reg > row0 + mloc) p[nt][reg] = 0.f;
        }
        for (int nt = 0; nt < 4; nt++)
            l_part += (p[nt][0] + p[nt][1]) + (p[nt][2] + p[nt][3]);

        // P -> LDS: 4 consecutive keys pack into one b64 write per nt
        for (int nt = 0; nt < 4; nt++) {
            bf16x4 pk;
            for (int reg = 0; reg < 4; reg++) pk[reg] = (__bf16)p[nt][reg];
            int s0 = nt * 32 + q4 * 8;
            int pc = (s0 >> 4) ^ x7;
            *(bf16x4*)((char*)Ps + (row0 + mloc) * 128 + pc * 16 + (s0 & 8)) = pk;
        }
        for (int kc = 0; kc < 2; kc++) {
            int sw = ((kc * 4 + q4) ^ x7) << 4;
            bf16x8 afr = *(const bf16x8*)((const char*)Ps + (row0 + mloc) * 128 + sw);
            for (int nt = 0; nt < 4; nt++) {
                bf16x8 bfr = *(const bf16x8*)(Vb + (nt * 16 + mloc) * 128 + sw);
                o_acc[nt] = __builtin_amdgcn_mfma_f32_16x16x32_bf16(afr, bfr, o_acc[nt], 0, 0, 0);
            }
        }
    }

    // finalize l: lane holds partial for query m=mloc over its 64-key slices
    l_part += __shfl_xor(l_part, 16);
    l_part += __shfl_xor(l_part, 32);

    // degenerate rows: l==0 <=> entire causal window masked. Reference then
    // softmaxes uniformly over {window} U {unmasked future} (all at -1e9).
    unsigned long long bal = __ballot(l_part == 0.0f);
    unsigned degmask = (unsigned)(bal & 0xFFFFull);

    int* flagp = (int*)Ps;
    if (tid == 0) *flagp = 0;
    __syncthreads();
    if (lane == 0 && degmask) *flagp = 1;
    __syncthreads();
    int dflag = *flagp;

    if (dflag) {
        float l2 = 0.f;
        bool degrow = (degmask >> mloc) & 1;
        int qrow = qb * 64 + row0 + mloc;
        prefetchV(0);
        prefetchV(1);
        __syncthreads();
        for (int kb = 0; kb < 32; kb++) {
            if (kb == 31) wb_drain(); else wb_leave2();
            if (kb + 2 < 32) prefetchV(kb + 2);
            const char* Vb = (const char*)Vs[kb % 3];
            for (int kc = 0; kc < 2; kc++) {
                const float* vmp = &vms[kb * 64 + kc * 32 + q4 * 8];
                float4 va = *(const float4*)vmp;
                float4 vb4 = *(const float4*)(vmp + 4);
                float vmj[8] = {va.x, va.y, va.z, va.w, vb4.x, vb4.y, vb4.z, vb4.w};
                int kg0 = kb * 64 + kc * 32 + q4 * 8;
                bf16x8 af;
                float cnt = 0.f;
                for (int j = 0; j < 8; j++) {
                    float ind = degrow ? ((kg0 + j <= qrow) ? 1.0f : vmj[j]) : 0.0f;
                    af[j] = (__bf16)ind;
                    cnt += ind;
                }
                l2 += cnt;
                int sw = ((kc * 4 + q4) ^ x7) << 4;
                for (int nt = 0; nt < 4; nt++) {
                    bf16x8 bfr = *(const bf16x8*)(Vb + (nt * 16 + mloc) * 128 + sw);
                    o_acc[nt] = __builtin_amdgcn_mfma_f32_16x16x32_bf16(af, bfr, o_acc[nt], 0, 0, 0);
                }
            }
        }
        l2 += __shfl_xor(l2, 16);
        l2 += __shfl_xor(l2, 32);
        if (l_part == 0.0f) l_part = l2;
    }

    // epilogue: o_acc rows m = rowoff+reg; l lives in lane (m) -> shfl
    for (int reg = 0; reg < 4; reg++) {
        float lv = __shfl(l_part, rowoff + reg);
        int qg = qb * 64 + row0 + rowoff + reg;
        float qm = q_mask[b * S_LEN + qg];
        float inv = qm / lv;
        for (int nt = 0; nt < 4; nt++)
            out[((size_t)(b * S_LEN + qg)) * (NHEAD * 64) + h * 64 + nt * 16 + mloc] =
                o_acc[nt][reg] * inv;
    }
}

// ---------------- launch ------------------------------------------------------
extern "C" void kernel_launch(void* const* d_in, const int* in_sizes, int n_in,
                              void* d_out, int out_size, void* d_ws, size_t ws_size,
                              hipStream_t stream)
{
    const float* q      = (const float*)d_in[0];
    const float* k      = (const float*)d_in[1];
    const float* v      = (const float*)d_in[2];
    const float* v_mask = (const float*)d_in[3];
    const float* q_mask = (const float*)d_in[4];
    const float* Wq     = (const float*)d_in[5];
    const float* Wk     = (const float*)d_in[6];
    const float* Wv     = (const float*)d_in[7];
    float* out = (float*)d_out;

    __bf16* Abf = (__bf16*)d_ws;                 // 3 x 8192 x 1024
    __bf16* Wt  = Abf + (size_t)3 * 8388608;     // 3 x 1024 x 1024
    __bf16* qw  = Wt + (size_t)3 * 1048576;      // [B*H][S][64] (x0.125)
    __bf16* kw  = qw + (size_t)8388608;
    __bf16* vt  = kw + (size_t)8388608;          // [B*H][64][S]

    cast_swizzle_kernel<<<12288, 256, 0, stream>>>(q, k, v, Abf);
    transpose_cast_kernel<<<dim3(32, 32, 3), 256, 0, stream>>>(Wq, Wk, Wv, Wt);
    proj_gemm_kernel<<<dim3(64, 8, 3), 256, 0, stream>>>(Abf, Wt, qw, kw, vt);
    attn_kernel<<<dim3(32, 64), 256, 0, stream>>>(qw, kw, vt, v_mask, q_mask, out);
}

// Round 7
// 317.689 us; speedup vs baseline: 1.0595x; 1.0595x over previous
//
#include <hip/hip_runtime.h>

#define S_LEN 2048
#define NHEAD 16

typedef float f32x4 __attribute__((ext_vector_type(4)));
typedef __bf16 bf16x8 __attribute__((ext_vector_type(8)));
typedef __bf16 bf16x4 __attribute__((ext_vector_type(4)));

#define AS1 __attribute__((address_space(1)))
#define AS3 __attribute__((address_space(3)))

// async 16B/lane global->LDS; lds base wave-uniform (dest = base + lane*16)
__device__ __forceinline__ void gl2lds16(const void* g, void* l) {
    __builtin_amdgcn_global_load_lds((const AS1 unsigned int*)g,
                                     (AS3 unsigned int*)l, 16, 0, 0);
}
// barrier leaving newest N vmem loads in flight (proj kernel only)
__device__ __forceinline__ void wb_leave4() {
    asm volatile("s_waitcnt vmcnt(4)\n\ts_barrier" ::: "memory");
}
__device__ __forceinline__ void wb_drain() {
    asm volatile("s_waitcnt vmcnt(0)\n\ts_barrier" ::: "memory");
}

// ---------------- cast+swizzle A: q,k,v fp32[8192][1024] -> bf16, 16B chunks
// within each 64-elem k-segment permuted by (chunk ^ row&7) -------------------
__global__ __launch_bounds__(256) void cast_swizzle_kernel(
    const float* __restrict__ q, const float* __restrict__ k,
    const float* __restrict__ v, __bf16* __restrict__ out)
{
    int gid = blockIdx.x * 256 + threadIdx.x;
    int z   = gid >> 20;
    int rem = gid & 1048575;
    int r   = rem >> 7;
    int c   = rem & 127;
    const float* src = (z == 0 ? q : z == 1 ? k : v) + (size_t)r * 1024 + c * 8;
    float4 a = *(const float4*)src;
    float4 b = *(const float4*)(src + 4);
    bf16x8 t;
    t[0] = (__bf16)a.x; t[1] = (__bf16)a.y; t[2] = (__bf16)a.z; t[3] = (__bf16)a.w;
    t[4] = (__bf16)b.x; t[5] = (__bf16)b.y; t[6] = (__bf16)b.z; t[7] = (__bf16)b.w;
    int cp = (c & ~7) | ((c ^ r) & 7);
    *(bf16x8*)(out + (size_t)z * 8388608 + (size_t)r * 1024 + cp * 8) = t;
}

// ---------------- W transpose+cast+swizzle: W[k][n] f32 -> Wt[n][k] bf16 -----
__global__ __launch_bounds__(256) void transpose_cast_kernel(
    const float* __restrict__ W0, const float* __restrict__ W1,
    const float* __restrict__ W2, __bf16* __restrict__ Wt)
{
    int z = blockIdx.z;
    const float* W = (z == 0 ? W0 : z == 1 ? W1 : W2);
    __bf16* out = Wt + (size_t)z * 1048576;
    __shared__ float tile[32][33];
    int bx = blockIdx.x, by = blockIdx.y;
    int tid = threadIdx.x;
    int tx = tid & 31, ty = tid >> 5;
    for (int i = 0; i < 32; i += 8)
        tile[ty + i][tx] = W[(size_t)(by * 32 + ty + i) * 1024 + bx * 32 + tx];
    __syncthreads();
    if (tid < 128) {
        int nl = tid >> 2, kc = tid & 3;
        int n = bx * 32 + nl;
        int kbase = by * 32 + kc * 8;
        bf16x8 t;
        for (int j = 0; j < 8; j++) t[j] = (__bf16)tile[kc * 8 + j][nl];
        int cp = ((kbase >> 3) ^ n) & 7;
        *(bf16x8*)(out + (size_t)n * 1024 + (kbase & ~63) + cp * 8) = t;
    }
}

// ---------------- fused projection GEMM (z = 0:Q, 1:K, 2:V) ------------------
// BK=32, 3-slot LDS pipeline, 2-ahead prefetch, vmcnt-leave barriers.
// z==0 output pre-scaled by 0.125 (exact pow2; folds QK^T scale into Q).
__global__ __launch_bounds__(256, 3) void proj_gemm_kernel(
    const __bf16* __restrict__ Abf, const __bf16* __restrict__ Wt,
    __bf16* __restrict__ qw, __bf16* __restrict__ kw, __bf16* __restrict__ vt)
{
    int z = blockIdx.z;
    const __bf16* A = Abf + (size_t)z * 8388608;
    const __bf16* B = Wt + (size_t)z * 1048576;
    __shared__ __align__(16) char smem[49152];

    int tid = threadIdx.x;
    int bm = blockIdx.x, bn = blockIdx.y;
    int wave = tid >> 6, lane = tid & 63;
    int wm = (wave >> 1) * 64, wn = (wave & 1) * 64;
    int lrow = lane & 15;
    int q4 = lane >> 4;
    int l4r = lane >> 2, j4 = lane & 3;

    auto pf = [&](int kb) {
        int sl = kb % 3;
        int k0 = kb * 32;
        int segbyte = (k0 >> 6) * 128;
        int cbase = (k0 & 32) >> 3;
        for (int i = 0; i < 2; i++) {
            int r = wave * 32 + i * 16 + l4r;
            int cl = j4 ^ ((r >> 1) & 3);
            int phys = ((cbase + cl) ^ r) & 7;
            gl2lds16((const char*)A + (size_t)(bm * 128 + r) * 2048 + segbyte + phys * 16,
                     smem + sl * 8192 + wave * 2048 + i * 1024);
            gl2lds16((const char*)B + (size_t)(bn * 128 + r) * 2048 + segbyte + phys * 16,
                     smem + 24576 + sl * 8192 + wave * 2048 + i * 1024);
        }
    };

    f32x4 zero = {0.f, 0.f, 0.f, 0.f};
    f32x4 acc[4][4];
    for (int mt = 0; mt < 4; mt++)
        for (int nt = 0; nt < 4; nt++) acc[mt][nt] = zero;

    pf(0); pf(1);
    __syncthreads();
    for (int kb = 0; kb < 32; kb++) {
        if (kb == 31) wb_drain(); else wb_leave4();
        if (kb + 2 < 32) pf(kb + 2);
        int sA = (kb % 3) * 8192, sB = 24576 + (kb % 3) * 8192;
        bf16x8 af[4], bfv[4];
        for (int mt = 0; mt < 4; mt++) {
            int r = wm + mt * 16 + lrow;
            af[mt] = *(const bf16x8*)(smem + sA + r * 64 + (q4 ^ ((r >> 1) & 3)) * 16);
        }
        for (int nt = 0; nt < 4; nt++) {
            int r = wn + nt * 16 + lrow;
            bfv[nt] = *(const bf16x8*)(smem + sB + r * 64 + (q4 ^ ((r >> 1) & 3)) * 16);
        }
        for (int mt = 0; mt < 4; mt++)
            for (int nt = 0; nt < 4; nt++)
                acc[mt][nt] = __builtin_amdgcn_mfma_f32_16x16x32_bf16(
                    af[mt], bfv[nt], acc[mt][nt], 0, 0, 0);
    }
    __syncthreads();
    __bf16* T = (__bf16*)smem;     // row stride 136 elems (272 B)

    float oscale = (z == 0) ? 0.125f : 1.0f;
    int rowoff = q4 * 4;
    int b = bm >> 4;
    int s_base = (bm & 15) * 128;
    if (z < 2) {
        for (int mt = 0; mt < 4; mt++) {
            for (int nt = 0; nt < 4; nt++) {
                int n_local = wn + nt * 16 + lrow;
                int hl = n_local >> 6, d = n_local & 63;
                for (int reg = 0; reg < 4; reg++) {
                    int s_local = wm + mt * 16 + rowoff + reg;
                    int s = s_base + s_local;
                    int dp = (d & 7) | ((((d >> 3) ^ s) & 7) << 3);
                    T[s_local * 136 + hl * 64 + dp] = (__bf16)(acc[mt][nt][reg] * oscale);
                }
            }
        }
        __syncthreads();
        char* gq = (char*)(z == 0 ? qw : kw);
        for (int i = 0; i < 8; i++) {
            int id = tid + i * 256;
            int hl = id >> 10, r = (id >> 3) & 127, j = id & 7;
            float4 val = *(float4*)((char*)T + r * 272 + hl * 128 + j * 16);
            *(float4*)(gq + ((size_t)((b * 16 + bn * 2 + hl) * 2048) + s_base + r) * 128
                          + j * 16) = val;
        }
    } else {
        for (int mt = 0; mt < 4; mt++) {
            int s0 = wm + mt * 16 + rowoff;
            int seg = s0 >> 6, j0 = s0 & 63;
            for (int nt = 0; nt < 4; nt++) {
                int n_local = wn + nt * 16 + lrow;
                int d = n_local & 63;
                int hi = ((j0 >> 3) ^ d) & 7;
                bf16x4 pk;
                for (int reg = 0; reg < 4; reg++) pk[reg] = (__bf16)acc[mt][nt][reg];
                *(bf16x4*)&T[n_local * 136 + seg * 64 + hi * 8 + (j0 & 7)] = pk;
            }
        }
        __syncthreads();
        char* gv = (char*)vt;
        for (int i = 0; i < 8; i++) {
            int id = tid + i * 256;
            int nl = id >> 4, j = id & 15;
            int hl = nl >> 6, dv = nl & 63;
            float4 val = *(float4*)((char*)T + nl * 272 + j * 16);
            *(float4*)(gv + (((size_t)((b * 16 + bn * 2 + hl) * 64 + dv)) * 2048 + s_base) * 2
                          + j * 16) = val;
        }
    }
}

// ---------------- flash attention: wave-independent kv tiles, no main-loop
// barriers. Constant-max softmax => O,l linear in kv tiles => wave w handles
// kb = w, w+4, ... and partial (O,l) are summed at the end via LDS.
// All K/V/Q fragments loaded per-lane directly global->VGPR.
__global__ __launch_bounds__(256, 2) void attn_kernel(
    const __bf16* __restrict__ QW, const __bf16* __restrict__ KW,
    const __bf16* __restrict__ VT, const float* __restrict__ v_mask,
    const float* __restrict__ q_mask, float* __restrict__ out)
{
    int bx = blockIdx.x;
    int qb = (bx == 0) ? 0 : 32 - bx;   // deg-capable qb=0 first, then heavy
    int bh = blockIdx.y;
    int b = bh >> 4, h = bh & 15;

    __shared__ __align__(16) char lds[42256];
    char*  Pw   = lds;                      // 4 waves x 8KB P matrices
    float* vms  = (float*)(lds + 32768);    // v_mask row (8KB)
    float* lbuf = (float*)(lds + 40960);    // [64 query][4 wave]
    float* lfin = (float*)(lds + 41984);    // [64] final l
    int*   flag = (int*)(lds + 42240);

    int tid = threadIdx.x;
    int wave = tid >> 6, lane = tid & 63;
    int mloc = lane & 15;
    int q4 = lane >> 4;
    int rowoff = q4 * 4;
    int x7 = mloc & 7;
    char* Pme = Pw + wave * 8192;

    const char* Qrow = (const char*)QW + ((size_t)bh * 2048 + qb * 64) * 128;
    const char* Krow = (const char*)KW + (size_t)bh * 2048 * 128;
    const char* Vrow = (const char*)VT + (size_t)bh * 64 * 4096;

    if (tid == 0) *flag = 0;
    for (int i = 0; i < 2; i++)
        gl2lds16((const char*)v_mask + (size_t)b * 8192 + wave * 2048 + i * 1024 + lane * 16,
                 (char*)vms + wave * 2048 + i * 1024);

    // Q fragments: all 64 queries, per-lane direct loads (QW pre-scaled 0.125)
    bf16x8 qfr[4][2];
    for (int nt = 0; nt < 4; nt++)
        for (int kc = 0; kc < 2; kc++)
            qfr[nt][kc] = *(const bf16x8*)(Qrow + (nt * 16 + mloc) * 128 +
                                           (((kc * 4 + q4) ^ x7) << 4));
    __syncthreads();   // vms resident; flag cleared

    f32x4 zero = {0.f, 0.f, 0.f, 0.f};
    f32x4 o_acc[4][4];
    for (int mt = 0; mt < 4; mt++)
        for (int nt = 0; nt < 4; nt++) o_acc[mt][nt] = zero;
    float lt[4] = {0.f, 0.f, 0.f, 0.f};

    for (int kb = wave; kb <= qb; kb += 4) {
        // V fragments early (used ~500 cyc later in PV)
        bf16x8 vfr[4][2];
        for (int nt = 0; nt < 4; nt++)
            for (int kc = 0; kc < 2; kc++)
                vfr[nt][kc] = *(const bf16x8*)(Vrow + (size_t)(nt * 16 + mloc) * 4096 +
                                               kb * 128 + (((kc * 4 + q4) ^ x7) << 4));
        // S^T in two key-halves to cap live sacc regs
        for (int half = 0; half < 2; half++) {
            bf16x8 kfr[2][2];
            for (int m2 = 0; m2 < 2; m2++)
                for (int kc = 0; kc < 2; kc++)
                    kfr[m2][kc] = *(const bf16x8*)(Krow +
                        (size_t)(kb * 64 + (half * 2 + m2) * 16 + mloc) * 128 +
                        (((kc * 4 + q4) ^ x7) << 4));
            f32x4 sacc[2][4];
            for (int m2 = 0; m2 < 2; m2++)
                for (int nt = 0; nt < 4; nt++) sacc[m2][nt] = zero;
            for (int kc = 0; kc < 2; kc++)
                for (int m2 = 0; m2 < 2; m2++)
                    for (int nt = 0; nt < 4; nt++)
                        sacc[m2][nt] = __builtin_amdgcn_mfma_f32_16x16x32_bf16(
                            kfr[m2][kc], qfr[nt][kc], sacc[m2][nt], 0, 0, 0);
            for (int m2 = 0; m2 < 2; m2++) {
                int mt = half * 2 + m2;
                float4 vm4 = *(const float4*)&vms[kb * 64 + mt * 16 + rowoff];
                float pen[4];
                pen[0] = fmaf(1.0f - vm4.x, 1.0e9f, 12.0f);
                pen[1] = fmaf(1.0f - vm4.y, 1.0e9f, 12.0f);
                pen[2] = fmaf(1.0f - vm4.z, 1.0e9f, 12.0f);
                pen[3] = fmaf(1.0f - vm4.w, 1.0e9f, 12.0f);
                for (int nt = 0; nt < 4; nt++) {
                    float p[4];
                    for (int reg = 0; reg < 4; reg++)
                        p[reg] = __expf(sacc[m2][nt][reg] - pen[reg]);
                    if (kb == qb)   // causal zeroing on diagonal tile
                        for (int reg = 0; reg < 4; reg++)
                            if (mt * 16 + rowoff + reg > nt * 16 + mloc) p[reg] = 0.f;
                    lt[nt] += (p[0] + p[1]) + (p[2] + p[3]);
                    bf16x4 pk;
                    for (int reg = 0; reg < 4; reg++) pk[reg] = (__bf16)p[reg];
                    *(bf16x4*)(Pme + (nt * 16 + mloc) * 128 +
                               ((((mt * 2 + (q4 >> 1)) ^ x7)) << 4) + (q4 & 1) * 8) = pk;
                }
            }
        }
        // O += P V  (P from wave-private LDS; no barriers anywhere)
        for (int mtq = 0; mtq < 4; mtq++)
            for (int kc = 0; kc < 2; kc++) {
                bf16x8 afr = *(const bf16x8*)(Pme + (mtq * 16 + mloc) * 128 +
                                              (((kc * 4 + q4) ^ x7) << 4));
                for (int nt = 0; nt < 4; nt++)
                    o_acc[mtq][nt] = __builtin_amdgcn_mfma_f32_16x16x32_bf16(
                        afr, vfr[nt][kc], o_acc[mtq][nt], 0, 0, 0);
            }
    }

    // reduce l within wave (keys split by q4), exchange across waves
    for (int nt = 0; nt < 4; nt++) {
        lt[nt] += __shfl_xor(lt[nt], 16);
        lt[nt] += __shfl_xor(lt[nt], 32);
    }
    if (q4 == 0)
        for (int nt = 0; nt < 4; nt++)
            lbuf[(nt * 16 + mloc) * 4 + wave] = lt[nt];
    __syncthreads();
    float ltot[4];
    bool mydeg = false;
    for (int nt = 0; nt < 4; nt++) {
        float4 lv = *(const float4*)&lbuf[(nt * 16 + mloc) * 4];
        ltot[nt] = (lv.x + lv.y) + (lv.z + lv.w);
        mydeg |= (ltot[nt] == 0.0f);
    }
    if (mydeg && lane == 0) *flag = 1;
    __syncthreads();

    if (*flag) {
        // degenerate queries (entire causal window masked): reference softmaxes
        // uniformly over {window} U {unmasked future} (all logits exactly -1e9).
        // Indicator pass, distributed over waves like the main loop.
        float l2[4] = {0.f, 0.f, 0.f, 0.f};
        for (int kb = wave; kb < 32; kb += 4) {
            bf16x8 vfr[4][2];
            for (int nt = 0; nt < 4; nt++)
                for (int kc = 0; kc < 2; kc++)
                    vfr[nt][kc] = *(const bf16x8*)(Vrow + (size_t)(nt * 16 + mloc) * 4096 +
                                                   kb * 128 + (((kc * 4 + q4) ^ x7) << 4));
            for (int kc = 0; kc < 2; kc++) {
                const float* vmp = &vms[kb * 64 + kc * 32 + q4 * 8];
                float4 va = *(const float4*)vmp;
                float4 vb4 = *(const float4*)(vmp + 4);
                float vmj[8] = {va.x, va.y, va.z, va.w, vb4.x, vb4.y, vb4.z, vb4.w};
                int kg0 = kb * 64 + kc * 32 + q4 * 8;
                for (int mtq = 0; mtq < 4; mtq++) {
                    bool degrow = (ltot[mtq] == 0.0f);
                    int qrow = qb * 64 + mtq * 16 + mloc;
                    bf16x8 af;
                    float cnt = 0.f;
                    for (int j = 0; j < 8; j++) {
                        float ind = degrow ? ((kg0 + j <= qrow) ? 1.0f : vmj[j]) : 0.0f;
                        af[j] = (__bf16)ind;
                        cnt += ind;
                    }
                    l2[mtq] += cnt;
                    for (int nt = 0; nt < 4; nt++)
                        o_acc[mtq][nt] = __builtin_amdgcn_mfma_f32_16x16x32_bf16(
                            af, vfr[nt][kc], o_acc[mtq][nt], 0, 0, 0);
                }
            }
        }
        for (int mtq = 0; mtq < 4; mtq++) {
            l2[mtq] += __shfl_xor(l2[mtq], 16);
            l2[mtq] += __shfl_xor(l2[mtq], 32);
        }
        if (q4 == 0)
            for (int mtq = 0; mtq < 4; mtq++)
                lbuf[(mtq * 16 + mloc) * 4 + wave] = l2[mtq];
        __syncthreads();
        for (int nt = 0; nt < 4; nt++) {
            if (ltot[nt] == 0.0f) {
                float4 lv = *(const float4*)&lbuf[(nt * 16 + mloc) * 4];
                ltot[nt] = (lv.x + lv.y) + (lv.z + lv.w);
            }
        }
    }

    // publish final l (all lanes agree; wave 0 q4==0 writes)
    if (wave == 0 && q4 == 0)
        for (int nt = 0; nt < 4; nt++)
            lfin[nt * 16 + mloc] = ltot[nt];

    // O reduction across waves in 2 chunks of 32 queries, then scaled store
    for (int ch = 0; ch < 2; ch++) {
        float* Tme = (float*)Pme;
        for (int mtl = 0; mtl < 2; mtl++) {
            int mtq = ch * 2 + mtl;
            for (int nt = 0; nt < 4; nt++)
                for (int reg = 0; reg < 4; reg++)
                    Tme[(mtl * 16 + rowoff + reg) * 64 + nt * 16 + mloc] =
                        o_acc[mtq][nt][reg];
        }
        __syncthreads();
        int q_rel = tid >> 3;
        int dv0 = (tid & 7) * 8;
        int qg = qb * 64 + ch * 32 + q_rel;
        float4 s0 = {0.f, 0.f, 0.f, 0.f}, s1 = {0.f, 0.f, 0.f, 0.f};
        for (int w = 0; w < 4; w++) {
            const float* base = (const float*)(Pw + w * 8192) + q_rel * 64 + dv0;
            float4 a = *(const float4*)base;
            float4 c = *(const float4*)(base + 4);
            s0.x += a.x; s0.y += a.y; s0.z += a.z; s0.w += a.w;
            s1.x += c.x; s1.y += c.y; s1.z += c.z; s1.w += c.w;
        }
        float scale = q_mask[b * 2048 + qg] / lfin[ch * 32 + q_rel];
        s0.x *= scale; s0.y *= scale; s0.z *= scale; s0.w *= scale;
        s1.x *= scale; s1.y *= scale; s1.z *= scale; s1.w *= scale;
        float* op = out + ((size_t)(b * 2048 + qg)) * 1024 + h * 64 + dv0;
        *(float4*)op = s0;
        *(float4*)(op + 4) = s1;
        __syncthreads();
    }
}

// ---------------- launch ------------------------------------------------------
extern "C" void kernel_launch(void* const* d_in, const int* in_sizes, int n_in,
                              void* d_out, int out_size, void* d_ws, size_t ws_size,
                              hipStream_t stream)
{
    const float* q      = (const float*)d_in[0];
    const float* k      = (const float*)d_in[1];
    const float* v      = (const float*)d_in[2];
    const float* v_mask = (const float*)d_in[3];
    const float* q_mask = (const float*)d_in[4];
    const float* Wq     = (const float*)d_in[5];
    const float* Wk     = (const float*)d_in[6];
    const float* Wv     = (const float*)d_in[7];
    float* out = (float*)d_out;

    __bf16* Abf = (__bf16*)d_ws;                 // 3 x 8192 x 1024
    __bf16* Wt  = Abf + (size_t)3 * 8388608;     // 3 x 1024 x 1024
    __bf16* qw  = Wt + (size_t)3 * 1048576;      // [B*H][S][64] (x0.125)
    __bf16* kw  = qw + (size_t)8388608;
    __bf16* vt  = kw + (size_t)8388608;          // [B*H][64][S]

    cast_swizzle_kernel<<<12288, 256, 0, stream>>>(q, k, v, Abf);
    transpose_cast_kernel<<<dim3(32, 32, 3), 256, 0, stream>>>(Wq, Wk, Wv, Wt);
    proj_gemm_kernel<<<dim3(64, 8, 3), 256, 0, stream>>>(Abf, Wt, qw, kw, vt);
    attn_kernel<<<dim3(32, 64), 256, 0, stream>>>(qw, kw, vt, v_mask, q_mask, out);
}